// Round 1
// baseline (100.568 us; speedup 1.0000x reference)
//
#include <hip/hip_runtime.h>
#include <math.h>

#define NPROTO 10
#define NCLS 10
#define NPATCH 196
#define ROW_ELEMS 784
#define WT_STRIDE 12          // 10 classes padded to 12 for 48B-aligned float4 loads
#define TILE_ROWS 16
#define WT_ELEMS (NPROTO * NPATCH * WT_STRIDE)   // 23520 floats
#define TABLE_OFF WT_ELEMS                        // 80 floats: per proto [cy0..3, sy0..3]

// ---------- prep: transpose W and build sin/cos table for prototypes ----------
__global__ __launch_bounds__(256) void quanv_prep(
    const float* __restrict__ W, const float* __restrict__ protos,
    float* __restrict__ ws) {
  int idx = blockIdx.x * 256 + threadIdx.x;
  if (idx < WT_ELEMS) {
    int pp = idx / WT_STRIDE;            // proto*196 + p
    int c  = idx - pp * WT_STRIDE;
    ws[idx] = (c < NCLS) ? W[c * (NPROTO * NPATCH) + pp] : 0.0f;
  }
  if (idx < NPROTO * 8) {
    int proto = idx >> 3;
    int j = idx & 7;
    float h = 0.5f * protos[proto * 4 + (j & 3)];
    ws[TABLE_OFF + idx] = (j < 4) ? __cosf(h) : __sinf(h);
  }
}

// ---------- main fused kernel ----------
__global__ __launch_bounds__(256) void quanv_main(
    const float* __restrict__ x, const float* __restrict__ Wt,
    const float* __restrict__ table, const float* __restrict__ bias,
    float* __restrict__ out) {
  __shared__ float lds_x[TILE_ROWS * ROW_ELEMS];   // 50176 B

  const int tid = threadIdx.x;
  const int bx  = blockIdx.x;

  // Stage 16 rows, coalesced float4 (3136 float4 per block)
  const float4* gsrc = (const float4*)(x + (size_t)bx * TILE_ROWS * ROW_ELEMS);
  float4* ldst = (float4*)lds_x;
  #pragma unroll
  for (int i = 0; i < 13; ++i) {
    int idx = tid + i * 256;
    if (idx < TILE_ROWS * ROW_ELEMS / 4) ldst[idx] = gsrc[idx];
  }
  __syncthreads();

  const int wave = tid >> 6;
  const int lane = tid & 63;
  const int rr   = lane >> 4;     // row within wave's 4-row group
  const int p4   = lane & 15;     // patch sub-index
  const int trow = wave * 4 + rr; // tile row
  const float* row = &lds_x[trow * ROW_ELEMS];

  float acc[NCLS];
  #pragma unroll
  for (int c = 0; c < NCLS; ++c) acc[c] = 0.0f;

  for (int it = 0; it < 13; ++it) {
    int p = it * 16 + p4;
    if (p < NPATCH) {
      unsigned up = (unsigned)p;
      int pi = up / 14u;
      int pj = up - pi * 14u;
      int off = pi * 56 + pj * 2;
      float x0 = row[off],      x1 = row[off + 1];
      float x2 = row[off + 28], x3 = row[off + 29];
      float s0 = __sinf(0.5f * x0), c0 = __cosf(0.5f * x0);
      float s1 = __sinf(0.5f * x1), c1 = __cosf(0.5f * x1);
      float s2 = __sinf(0.5f * x2), c2 = __cosf(0.5f * x2);
      float s3 = __sinf(0.5f * x3), c3 = __cosf(0.5f * x3);

      #pragma unroll
      for (int proto = 0; proto < NPROTO; ++proto) {
        const float* tb = table + proto * 8;   // uniform -> s_load
        float t0 = c0 * tb[0] + s0 * tb[4];
        float t1 = c1 * tb[1] + s1 * tb[5];
        float t2 = c2 * tb[2] + s2 * tb[6];
        float t3 = c3 * tb[3] + s3 * tb[7];
        float q = fabsf(t0 * t1 * t2 * t3);

        const float* wp = Wt + (size_t)(proto * NPATCH + p) * WT_STRIDE;
        float4 wa = *(const float4*)(wp);
        float4 wb = *(const float4*)(wp + 4);
        float2 wc = *(const float2*)(wp + 8);
        acc[0] += q * wa.x; acc[1] += q * wa.y;
        acc[2] += q * wa.z; acc[3] += q * wa.w;
        acc[4] += q * wb.x; acc[5] += q * wb.y;
        acc[6] += q * wb.z; acc[7] += q * wb.w;
        acc[8] += q * wc.x; acc[9] += q * wc.y;
      }
    }
  }

  // Reduce across the 16 lanes (p4) of each row group
  #pragma unroll
  for (int c = 0; c < NCLS; ++c) {
    float v = acc[c];
    v += __shfl_xor(v, 1);
    v += __shfl_xor(v, 2);
    v += __shfl_xor(v, 4);
    v += __shfl_xor(v, 8);
    acc[c] = v + bias[c];
  }

  // log_softmax over the 10 classes (every lane has the full vector)
  float m = acc[0];
  #pragma unroll
  for (int c = 1; c < NCLS; ++c) m = fmaxf(m, acc[c]);
  float sum = 0.0f;
  #pragma unroll
  for (int c = 0; c < NCLS; ++c) sum += __expf(acc[c] - m);
  float lse = m + __logf(sum);

  if (p4 < NCLS) {
    float v = acc[0];
    #pragma unroll
    for (int c = 1; c < NCLS; ++c) v = (p4 == c) ? acc[c] : v;
    int grow = bx * TILE_ROWS + trow;
    out[grow * NCLS + p4] = v - lse;
  }
}

extern "C" void kernel_launch(void* const* d_in, const int* in_sizes, int n_in,
                              void* d_out, int out_size, void* d_ws, size_t ws_size,
                              hipStream_t stream) {
  const float* x      = (const float*)d_in[0];
  const float* protos = (const float*)d_in[1];
  const float* W      = (const float*)d_in[2];
  const float* bias   = (const float*)d_in[3];
  float* out = (float*)d_out;
  float* ws  = (float*)d_ws;

  quanv_prep<<<(WT_ELEMS + 255) / 256, 256, 0, stream>>>(W, protos, ws);
  quanv_main<<<8192 / TILE_ROWS, 256, 0, stream>>>(x, ws, ws + TABLE_OFF, bias, out);
}